// Round 3
// baseline (302.594 us; speedup 1.0000x reference)
//
#include <hip/hip_runtime.h>
#include <hip/hip_bf16.h>

#define D64 64

__device__ inline float lane_bcast(float v, int l) {
    return __uint_as_float(__builtin_amdgcn_readlane(__float_as_uint(v), l));
}

// out[r][a] = (relu?) sum_d in[r][d] * W[a][d]   (W row-major [64][64])
// in/out intentionally NOT __restrict__ (final call runs in place on d_out).
template<bool RELU>
__global__ void rowmm_kernel(const float* in, const float* __restrict__ W,
                             float* out, int nrows) {
    __shared__ float WT[D64 * D64];  // WT[d][a] = W[a][d]
    int tid = threadIdx.x;
    for (int i = tid; i < D64 * D64; i += blockDim.x)
        WT[(i & 63) * D64 + (i >> 6)] = W[i];
    __syncthreads();
    int lane = tid & 63;
    int wid = (blockIdx.x * blockDim.x + tid) >> 6;
    int nw = (gridDim.x * blockDim.x) >> 6;
    for (int r = wid; r < nrows; r += nw) {
        float v = in[r * D64 + lane];
        float acc = 0.f;
#pragma unroll
        for (int d = 0; d < D64; ++d)
            acc = fmaf(lane_bcast(v, d), WT[d * D64 + lane], acc);
        if (RELU) acc = fmaxf(acc, 0.f);
        out[r * D64 + lane] = acc;
    }
}

// Per-relation tables: hrmap[r] = emb[mapping[r]]; hrW[r] = hrmap[r] @ Wr.T
// Per-query: qr_attn[q] = emb[mapping[q_rel[q]]] @ Wqr.T + Wqr_b
__global__ void prep_kernel(const float* __restrict__ emb, const int* __restrict__ mapping,
                            const int* __restrict__ q_rel,
                            const float* __restrict__ Wr, const float* __restrict__ Wqr,
                            const float* __restrict__ Wqr_b,
                            float* __restrict__ hrmap, float* __restrict__ hrW,
                            float* __restrict__ qr_attn, int nrel, int nq) {
    int b = blockIdx.x;
    int lane = threadIdx.x;
    if (b < nrel) {
        int m = mapping[b];
        float v = emb[m * D64 + lane];
        hrmap[b * D64 + lane] = v;
        float acc = 0.f;
#pragma unroll
        for (int d = 0; d < D64; ++d)
            acc = fmaf(lane_bcast(v, d), Wr[lane * D64 + d], acc);
        hrW[b * D64 + lane] = acc;
    } else {
        int q = b - nrel;
        if (q < nq) {
            int m = mapping[q_rel[q]];
            float v = emb[m * D64 + lane];
            float acc = Wqr_b[lane];
#pragma unroll
            for (int d = 0; d < D64; ++d)
                acc = fmaf(lane_bcast(v, d), Wqr[lane * D64 + d], acc);
            qr_attn[q * D64 + lane] = acc;
        }
    }
}

// comb[r*NQ + q][d] = hrW[r][d] + qr_attn[q][d]
__global__ void comb_kernel(const float* __restrict__ hrW, const float* __restrict__ qr_attn,
                            float* __restrict__ comb, int nrel, int nq) {
    int lane = threadIdx.x;
    for (int b = blockIdx.x; b < nrel * nq; b += gridDim.x) {
        int r = b / nq, q = b - r * nq;
        comb[b * D64 + lane] = hrW[r * D64 + lane] + qr_attn[q * D64 + lane];
    }
}

__global__ void hist_kernel(const int* __restrict__ edges, int* __restrict__ counts, int E) {
    int i = blockIdx.x * blockDim.x + threadIdx.x;
    if (i < E) atomicAdd(&counts[edges[i * 3 + 2]], 1);
}

// Block-level exclusive scan: 1024 elements/block (256 thr x 4).
__global__ void scan1_kernel(const int* __restrict__ counts, int* __restrict__ offs,
                             int* __restrict__ partials, int n) {
    __shared__ int tsum[256];
    int t = threadIdx.x;
    int base = blockIdx.x * 1024 + t * 4;
    int v[4];
    int s = 0;
#pragma unroll
    for (int i = 0; i < 4; ++i) {
        int idx = base + i;
        int c = (idx < n) ? counts[idx] : 0;
        v[i] = s;
        s += c;
    }
    tsum[t] = s;
    __syncthreads();
    for (int off = 1; off < 256; off <<= 1) {
        int y = (t >= off) ? tsum[t - off] : 0;
        __syncthreads();
        tsum[t] += y;
        __syncthreads();
    }
    int incl = tsum[t];
    int thread_prefix = incl - s;
    if (t == 255) partials[blockIdx.x] = incl;
#pragma unroll
    for (int i = 0; i < 4; ++i) {
        int idx = base + i;
        if (idx < n) offs[idx] = thread_prefix + v[i];
    }
}

__global__ void scan2_kernel(int* partials, int nb) {
    int t = threadIdx.x;
    int own = (t < nb) ? partials[t] : 0;
    int v = own;
    for (int off = 1; off < 64; off <<= 1) {
        int y = __shfl_up(v, off, 64);
        if (t >= off) v += y;
    }
    if (t < nb) partials[t] = v - own;
}

__global__ void scan3_kernel(int* __restrict__ offs, const int* __restrict__ partials, int n) {
    int base = blockIdx.x * 1024 + threadIdx.x;
    int add = partials[blockIdx.x];
#pragma unroll
    for (int i = 0; i < 4; ++i) {
        int idx = base + i * 256;
        if (idx < n) offs[idx] += add;
    }
}

// Wave-per-edge (grid-stride): compute alpha, scatter packed {sub|rel<<17, alpha}.
// Mutates offs so afterwards offs[n] == inclusive segment end of node n.
__global__ void alpha_scatter_kernel(const int* __restrict__ edges, const int* __restrict__ r_idx,
                                     const float* __restrict__ hsW, const float* __restrict__ comb,
                                     const float* __restrict__ walpha_w,
                                     const float* __restrict__ walpha_b,
                                     int* __restrict__ offs, int2* __restrict__ rec,
                                     int E, int nq) {
    int lane = threadIdx.x & 63;
    int wid = (blockIdx.x * blockDim.x + threadIdx.x) >> 6;
    int nw = (gridDim.x * blockDim.x) >> 6;
    float wa = walpha_w[lane];
    float wb = walpha_b[0];
    for (int e = wid; e < E; e += nw) {
        int sub = edges[e * 3 + 0];
        int rel = edges[e * 3 + 1];
        int obj = edges[e * 3 + 2];
        int ri  = r_idx[e];
        float pre = hsW[sub * D64 + lane] + comb[(rel * nq + ri) * D64 + lane];
        float x = fmaxf(pre, 0.f) * wa;
#pragma unroll
        for (int off = 32; off; off >>= 1) x += __shfl_xor(x, off, 64);
        float alpha = 1.f / (1.f + __expf(-(x + wb)));
        if (lane == 0) {
            int slot = atomicAdd(&offs[obj], 1);
            rec[slot] = make_int2(sub | (rel << 17), __float_as_int(alpha));
        }
    }
}

// One wave per destination node: light gather-FMA over its CSR segment.
__global__ void agg_kernel(const int2* __restrict__ rec, const int* __restrict__ endoff,
                           const float* __restrict__ hidden, const float* __restrict__ hrmap,
                           float* __restrict__ aggout, int NN) {
    int lane = threadIdx.x & 63;
    int wid = (blockIdx.x * blockDim.x + threadIdx.x) >> 6;
    if (wid >= NN) return;
    int n = wid;
    int start = (n == 0) ? 0 : endoff[n - 1];
    int end = endoff[n];
    // wave-uniform bounds -> scalar loop, scalar rec loads
    start = __builtin_amdgcn_readfirstlane(start);
    end = __builtin_amdgcn_readfirstlane(end);
    float acc = 0.f;
    int i = start;
    for (; i + 1 < end; i += 2) {
        int2 r0 = rec[i], r1 = rec[i + 1];
        int s0 = r0.x & 0x1FFFF, e0 = ((unsigned)r0.x) >> 17;
        int s1 = r1.x & 0x1FFFF, e1 = ((unsigned)r1.x) >> 17;
        float a0 = __int_as_float(r0.y);
        float a1 = __int_as_float(r1.y);
        acc = fmaf(a0 * hidden[s0 * D64 + lane], hrmap[e0 * D64 + lane], acc);
        acc = fmaf(a1 * hidden[s1 * D64 + lane], hrmap[e1 * D64 + lane], acc);
    }
    if (i < end) {
        int2 r0 = rec[i];
        int s0 = r0.x & 0x1FFFF, e0 = ((unsigned)r0.x) >> 17;
        float a0 = __int_as_float(r0.y);
        acc = fmaf(a0 * hidden[s0 * D64 + lane], hrmap[e0 * D64 + lane], acc);
    }
    aggout[n * D64 + lane] = acc;
}

extern "C" void kernel_launch(void* const* d_in, const int* in_sizes, int n_in,
                              void* d_out, int out_size, void* d_ws, size_t ws_size,
                              hipStream_t stream) {
    const float* hidden   = (const float*)d_in[0];
    const int*   edges    = (const int*)d_in[1];
    const float* emb_rel  = (const float*)d_in[2];
    const int*   mapping  = (const int*)d_in[3];
    const int*   q_rel    = (const int*)d_in[4];
    const int*   r_idx    = (const int*)d_in[5];
    const float* Ws_w     = (const float*)d_in[7];
    const float* Wr_w     = (const float*)d_in[8];
    const float* Wqr_w    = (const float*)d_in[9];
    const float* Wqr_b    = (const float*)d_in[10];
    const float* walpha_w = (const float*)d_in[11];
    const float* walpha_b = (const float*)d_in[12];
    const float* Wh_w     = (const float*)d_in[13];
    float* out = (float*)d_out;

    int NN   = in_sizes[0] / D64;   // 50000
    int E    = in_sizes[5];         // 800000
    int NREL = in_sizes[3];         // 475
    int NQ   = in_sizes[4];         // 32

    // workspace layout
    char* ws = (char*)d_ws;
    size_t off = 0;
    float* hsW = (float*)(ws + off);      off += (size_t)NN * D64 * sizeof(float);      // 12.8 MB
    int2*  rec = (int2*)(ws + off);       off += (size_t)E * sizeof(int2);              // 6.4 MB
    float* comb = (float*)(ws + off);     off += (size_t)NREL * NQ * D64 * sizeof(float); // 3.9 MB
    int* counts = (int*)(ws + off);       off += (size_t)NN * sizeof(int);              // 0.2 MB
    int* offs   = (int*)(ws + off);       off += (size_t)NN * sizeof(int);              // 0.2 MB
    int* partials = (int*)(ws + off);     off += 64 * sizeof(int);
    float* hrmap = (float*)(ws + off);    off += (size_t)NREL * D64 * sizeof(float);
    float* hrW   = (float*)(ws + off);    off += (size_t)NREL * D64 * sizeof(float);
    float* qr_attn = (float*)(ws + off);  off += (size_t)NQ * D64 * sizeof(float);

    int NB = (NN + 1023) / 1024;  // scan blocks (49)

    hipMemsetAsync(counts, 0, (size_t)NN * sizeof(int), stream);
    prep_kernel<<<NREL + NQ, 64, 0, stream>>>(emb_rel, mapping, q_rel, Wr_w, Wqr_w, Wqr_b,
                                              hrmap, hrW, qr_attn, NREL, NQ);
    comb_kernel<<<2048, 64, 0, stream>>>(hrW, qr_attn, comb, NREL, NQ);
    rowmm_kernel<false><<<1024, 256, 0, stream>>>(hidden, Ws_w, hsW, NN);
    hist_kernel<<<(E + 255) / 256, 256, 0, stream>>>(edges, counts, E);
    scan1_kernel<<<NB, 256, 0, stream>>>(counts, offs, partials, NN);
    scan2_kernel<<<1, 64, 0, stream>>>(partials, NB);
    scan3_kernel<<<NB, 256, 0, stream>>>(offs, partials, NN);
    alpha_scatter_kernel<<<2048, 256, 0, stream>>>(edges, r_idx, hsW, comb,
                                                   walpha_w, walpha_b, offs, rec, E, NQ);
    // aggregate straight into d_out, then apply Wh in place
    agg_kernel<<<(NN * 64 + 255) / 256, 256, 0, stream>>>(rec, offs, hidden, hrmap, out, NN);
    rowmm_kernel<true><<<1024, 256, 0, stream>>>(out, Wh_w, out, NN);
}

// Round 4
// 247.897 us; speedup vs baseline: 1.2206x; 1.2206x over previous
//
#include <hip/hip_runtime.h>
#include <hip/hip_bf16.h>

#define D64 64

__device__ inline float lane_bcast(float v, int l) {
    return __uint_as_float(__builtin_amdgcn_readlane(__float_as_uint(v), l));
}

// out[r][a] = (relu?) sum_d in[r][d] * W[a][d]   (W row-major [64][64])
// in/out intentionally NOT __restrict__ (final call runs in place on d_out).
template<bool RELU>
__global__ void rowmm_kernel(const float* in, const float* __restrict__ W,
                             float* out, int nrows) {
    __shared__ float WT[D64 * D64];  // WT[d][a] = W[a][d]
    int tid = threadIdx.x;
    for (int i = tid; i < D64 * D64; i += blockDim.x)
        WT[(i & 63) * D64 + (i >> 6)] = W[i];
    __syncthreads();
    int lane = tid & 63;
    int wid = (blockIdx.x * blockDim.x + tid) >> 6;
    int nw = (gridDim.x * blockDim.x) >> 6;
    for (int r = wid; r < nrows; r += nw) {
        float v = in[r * D64 + lane];
        float acc = 0.f;
#pragma unroll
        for (int d = 0; d < D64; ++d)
            acc = fmaf(lane_bcast(v, d), WT[d * D64 + lane], acc);
        if (RELU) acc = fmaxf(acc, 0.f);
        out[r * D64 + lane] = acc;
    }
}

// Per-relation tables: hrmap[r] = emb[mapping[r]]; hrW[r] = hrmap[r] @ Wr.T
// Per-query: qr_attn[q] = emb[mapping[q_rel[q]]] @ Wqr.T + Wqr_b
__global__ void prep_kernel(const float* __restrict__ emb, const int* __restrict__ mapping,
                            const int* __restrict__ q_rel,
                            const float* __restrict__ Wr, const float* __restrict__ Wqr,
                            const float* __restrict__ Wqr_b,
                            float* __restrict__ hrmap, float* __restrict__ hrW,
                            float* __restrict__ qr_attn, int nrel, int nq) {
    int b = blockIdx.x;
    int lane = threadIdx.x;
    if (b < nrel) {
        int m = mapping[b];
        float v = emb[m * D64 + lane];
        hrmap[b * D64 + lane] = v;
        float acc = 0.f;
#pragma unroll
        for (int d = 0; d < D64; ++d)
            acc = fmaf(lane_bcast(v, d), Wr[lane * D64 + d], acc);
        hrW[b * D64 + lane] = acc;
    } else {
        int q = b - nrel;
        if (q < nq) {
            int m = mapping[q_rel[q]];
            float v = emb[m * D64 + lane];
            float acc = Wqr_b[lane];
#pragma unroll
            for (int d = 0; d < D64; ++d)
                acc = fmaf(lane_bcast(v, d), Wqr[lane * D64 + d], acc);
            qr_attn[q * D64 + lane] = acc;
        }
    }
}

__global__ void hist_kernel(const int* __restrict__ edges, int* __restrict__ counts, int E) {
    int i = blockIdx.x * blockDim.x + threadIdx.x;
    if (i < E) atomicAdd(&counts[edges[i * 3 + 2]], 1);
}

// Block-level exclusive scan: 1024 elements/block (256 thr x 4).
__global__ void scan1_kernel(const int* __restrict__ counts, int* __restrict__ offs,
                             int* __restrict__ partials, int n) {
    __shared__ int tsum[256];
    int t = threadIdx.x;
    int base = blockIdx.x * 1024 + t * 4;
    int v[4];
    int s = 0;
#pragma unroll
    for (int i = 0; i < 4; ++i) {
        int idx = base + i;
        int c = (idx < n) ? counts[idx] : 0;
        v[i] = s;
        s += c;
    }
    tsum[t] = s;
    __syncthreads();
    for (int off = 1; off < 256; off <<= 1) {
        int y = (t >= off) ? tsum[t - off] : 0;
        __syncthreads();
        tsum[t] += y;
        __syncthreads();
    }
    int incl = tsum[t];
    int thread_prefix = incl - s;
    if (t == 255) partials[blockIdx.x] = incl;
#pragma unroll
    for (int i = 0; i < 4; ++i) {
        int idx = base + i;
        if (idx < n) offs[idx] = thread_prefix + v[i];
    }
}

__global__ void scan2_kernel(int* partials, int nb) {
    int t = threadIdx.x;
    int own = (t < nb) ? partials[t] : 0;
    int v = own;
    for (int off = 1; off < 64; off <<= 1) {
        int y = __shfl_up(v, off, 64);
        if (t >= off) v += y;
    }
    if (t < nb) partials[t] = v - own;
}

__global__ void scan3_kernel(int* __restrict__ offs, const int* __restrict__ partials, int n) {
    int base = blockIdx.x * 1024 + threadIdx.x;
    int add = partials[blockIdx.x];
#pragma unroll
    for (int i = 0; i < 4; ++i) {
        int idx = base + i * 256;
        if (idx < n) offs[idx] += add;
    }
}

// THREAD-per-edge: private float4 loop computes alpha (no cross-lane reduce),
// then scatters packed {sub|rel<<17, alpha_bits} into the obj-CSR slot.
// hrW (475 rows) and qr_attn (32 rows) are L1-resident; hsW[sub] is the one
// real gather (4 cache lines, kept hot across the 16-iteration loop).
// Mutates offs so afterwards offs[n] == inclusive segment end of node n.
__global__ void alpha_scatter_kernel(const int* __restrict__ edges, const int* __restrict__ r_idx,
                                     const float* __restrict__ hsW, const float* __restrict__ hrW,
                                     const float* __restrict__ qr_attn,
                                     const float* __restrict__ walpha_w,
                                     const float* __restrict__ walpha_b,
                                     int* __restrict__ offs, int2* __restrict__ rec, int E) {
    int e = blockIdx.x * blockDim.x + threadIdx.x;
    if (e >= E) return;
    int sub = edges[e * 3 + 0];
    int rel = edges[e * 3 + 1];
    int obj = edges[e * 3 + 2];
    int ri  = r_idx[e];
    const float4* a = (const float4*)(hsW + (size_t)sub * D64);
    const float4* b = (const float4*)(hrW + (size_t)rel * D64);
    const float4* c = (const float4*)(qr_attn + (size_t)ri * D64);
    const float4* w = (const float4*)walpha_w;
    float x = 0.f;
#pragma unroll
    for (int i = 0; i < 16; ++i) {
        float4 av = a[i], bv = b[i], cv = c[i], wv = w[i];
        x = fmaf(fmaxf(av.x + bv.x + cv.x, 0.f), wv.x, x);
        x = fmaf(fmaxf(av.y + bv.y + cv.y, 0.f), wv.y, x);
        x = fmaf(fmaxf(av.z + bv.z + cv.z, 0.f), wv.z, x);
        x = fmaf(fmaxf(av.w + bv.w + cv.w, 0.f), wv.w, x);
    }
    float alpha = 1.f / (1.f + __expf(-(x + walpha_b[0])));
    int slot = atomicAdd(&offs[obj], 1);
    rec[slot] = make_int2(sub | (rel << 17), __float_as_int(alpha));
}

// One wave per destination node: light gather-FMA over its CSR segment.
__global__ void agg_kernel(const int2* __restrict__ rec, const int* __restrict__ endoff,
                           const float* __restrict__ hidden, const float* __restrict__ hrmap,
                           float* __restrict__ aggout, int NN) {
    int lane = threadIdx.x & 63;
    int wid = (blockIdx.x * blockDim.x + threadIdx.x) >> 6;
    if (wid >= NN) return;
    int n = wid;
    int start = (n == 0) ? 0 : endoff[n - 1];
    int end = endoff[n];
    // wave-uniform bounds -> scalar loop, scalar rec loads
    start = __builtin_amdgcn_readfirstlane(start);
    end = __builtin_amdgcn_readfirstlane(end);
    float acc = 0.f;
    int i = start;
    for (; i + 1 < end; i += 2) {
        int2 r0 = rec[i], r1 = rec[i + 1];
        int s0 = r0.x & 0x1FFFF, e0 = ((unsigned)r0.x) >> 17;
        int s1 = r1.x & 0x1FFFF, e1 = ((unsigned)r1.x) >> 17;
        float a0 = __int_as_float(r0.y);
        float a1 = __int_as_float(r1.y);
        acc = fmaf(a0 * hidden[s0 * D64 + lane], hrmap[e0 * D64 + lane], acc);
        acc = fmaf(a1 * hidden[s1 * D64 + lane], hrmap[e1 * D64 + lane], acc);
    }
    if (i < end) {
        int2 r0 = rec[i];
        int s0 = r0.x & 0x1FFFF, e0 = ((unsigned)r0.x) >> 17;
        float a0 = __int_as_float(r0.y);
        acc = fmaf(a0 * hidden[s0 * D64 + lane], hrmap[e0 * D64 + lane], acc);
    }
    aggout[n * D64 + lane] = acc;
}

extern "C" void kernel_launch(void* const* d_in, const int* in_sizes, int n_in,
                              void* d_out, int out_size, void* d_ws, size_t ws_size,
                              hipStream_t stream) {
    const float* hidden   = (const float*)d_in[0];
    const int*   edges    = (const int*)d_in[1];
    const float* emb_rel  = (const float*)d_in[2];
    const int*   mapping  = (const int*)d_in[3];
    const int*   q_rel    = (const int*)d_in[4];
    const int*   r_idx    = (const int*)d_in[5];
    const float* Ws_w     = (const float*)d_in[7];
    const float* Wr_w     = (const float*)d_in[8];
    const float* Wqr_w    = (const float*)d_in[9];
    const float* Wqr_b    = (const float*)d_in[10];
    const float* walpha_w = (const float*)d_in[11];
    const float* walpha_b = (const float*)d_in[12];
    const float* Wh_w     = (const float*)d_in[13];
    float* out = (float*)d_out;

    int NN   = in_sizes[0] / D64;   // 50000
    int E    = in_sizes[5];         // 800000
    int NREL = in_sizes[3];         // 475
    int NQ   = in_sizes[4];         // 32

    // workspace layout
    char* ws = (char*)d_ws;
    size_t off = 0;
    float* hsW = (float*)(ws + off);      off += (size_t)NN * D64 * sizeof(float);   // 12.8 MB
    int2*  rec = (int2*)(ws + off);       off += (size_t)E * sizeof(int2);           // 6.4 MB
    int* counts = (int*)(ws + off);       off += (size_t)NN * sizeof(int);           // 0.2 MB
    int* offs   = (int*)(ws + off);       off += (size_t)NN * sizeof(int);           // 0.2 MB
    int* partials = (int*)(ws + off);     off += 64 * sizeof(int);
    float* hrmap = (float*)(ws + off);    off += (size_t)NREL * D64 * sizeof(float);
    float* hrW   = (float*)(ws + off);    off += (size_t)NREL * D64 * sizeof(float);
    float* qr_attn = (float*)(ws + off);  off += (size_t)NQ * D64 * sizeof(float);

    int NB = (NN + 1023) / 1024;  // scan blocks (49)

    hipMemsetAsync(counts, 0, (size_t)NN * sizeof(int), stream);
    prep_kernel<<<NREL + NQ, 64, 0, stream>>>(emb_rel, mapping, q_rel, Wr_w, Wqr_w, Wqr_b,
                                              hrmap, hrW, qr_attn, NREL, NQ);
    rowmm_kernel<false><<<1024, 256, 0, stream>>>(hidden, Ws_w, hsW, NN);
    hist_kernel<<<(E + 255) / 256, 256, 0, stream>>>(edges, counts, E);
    scan1_kernel<<<NB, 256, 0, stream>>>(counts, offs, partials, NN);
    scan2_kernel<<<1, 64, 0, stream>>>(partials, NB);
    scan3_kernel<<<NB, 256, 0, stream>>>(offs, partials, NN);
    alpha_scatter_kernel<<<(E + 255) / 256, 256, 0, stream>>>(edges, r_idx, hsW, hrW, qr_attn,
                                                              walpha_w, walpha_b, offs, rec, E);
    // aggregate straight into d_out, then apply Wh in place
    agg_kernel<<<(NN * 64 + 255) / 256, 256, 0, stream>>>(rec, offs, hidden, hrmap, out, NN);
    rowmm_kernel<true><<<1024, 256, 0, stream>>>(out, Wh_w, out, NN);
}

// Round 5
// 199.885 us; speedup vs baseline: 1.5138x; 1.2402x over previous
//
#include <hip/hip_runtime.h>
#include <hip/hip_bf16.h>

#define D64 64

__device__ inline float lane_bcast(float v, int l) {
    return __uint_as_float(__builtin_amdgcn_readlane(__float_as_uint(v), l));
}

// out[r][a] = (relu?) sum_d in[r][d] * W[a][d]   (W row-major [64][64])
// in/out intentionally NOT __restrict__ (final call runs in place on d_out).
template<bool RELU>
__global__ void rowmm_kernel(const float* in, const float* __restrict__ W,
                             float* out, int nrows) {
    __shared__ float WT[D64 * D64];  // WT[d][a] = W[a][d]
    int tid = threadIdx.x;
    for (int i = tid; i < D64 * D64; i += blockDim.x)
        WT[(i & 63) * D64 + (i >> 6)] = W[i];
    __syncthreads();
    int lane = tid & 63;
    int wid = (blockIdx.x * blockDim.x + tid) >> 6;
    int nw = (gridDim.x * blockDim.x) >> 6;
    for (int r = wid; r < nrows; r += nw) {
        float v = in[r * D64 + lane];
        float acc = 0.f;
#pragma unroll
        for (int d = 0; d < D64; ++d)
            acc = fmaf(lane_bcast(v, d), WT[d * D64 + lane], acc);
        if (RELU) acc = fmaxf(acc, 0.f);
        out[r * D64 + lane] = acc;
    }
}

// Per-relation tables: hrmap[r] = emb[mapping[r]]; hrW[r] = hrmap[r] @ Wr.T
// Per-query: qr_attn[q] = emb[mapping[q_rel[q]]] @ Wqr.T + Wqr_b
__global__ void prep_kernel(const float* __restrict__ emb, const int* __restrict__ mapping,
                            const int* __restrict__ q_rel,
                            const float* __restrict__ Wr, const float* __restrict__ Wqr,
                            const float* __restrict__ Wqr_b,
                            float* __restrict__ hrmap, float* __restrict__ hrW,
                            float* __restrict__ qr_attn, int nrel, int nq) {
    int b = blockIdx.x;
    int lane = threadIdx.x;
    if (b < nrel) {
        int m = mapping[b];
        float v = emb[m * D64 + lane];
        hrmap[b * D64 + lane] = v;
        float acc = 0.f;
#pragma unroll
        for (int d = 0; d < D64; ++d)
            acc = fmaf(lane_bcast(v, d), Wr[lane * D64 + d], acc);
        hrW[b * D64 + lane] = acc;
    } else {
        int q = b - nrel;
        if (q < nq) {
            int m = mapping[q_rel[q]];
            float v = emb[m * D64 + lane];
            float acc = Wqr_b[lane];
#pragma unroll
            for (int d = 0; d < D64; ++d)
                acc = fmaf(lane_bcast(v, d), Wqr[lane * D64 + d], acc);
            qr_attn[q * D64 + lane] = acc;
        }
    }
}

__global__ void hist_kernel(const int* __restrict__ edges, int* __restrict__ counts, int E) {
    int i = blockIdx.x * blockDim.x + threadIdx.x;
    if (i < E) atomicAdd(&counts[edges[i * 3 + 2]], 1);
}

// Block-level exclusive scan: 1024 elements/block (256 thr x 4).
__global__ void scan1_kernel(const int* __restrict__ counts, int* __restrict__ offs,
                             int* __restrict__ partials, int n) {
    __shared__ int tsum[256];
    int t = threadIdx.x;
    int base = blockIdx.x * 1024 + t * 4;
    int v[4];
    int s = 0;
#pragma unroll
    for (int i = 0; i < 4; ++i) {
        int idx = base + i;
        int c = (idx < n) ? counts[idx] : 0;
        v[i] = s;
        s += c;
    }
    tsum[t] = s;
    __syncthreads();
    for (int off = 1; off < 256; off <<= 1) {
        int y = (t >= off) ? tsum[t - off] : 0;
        __syncthreads();
        tsum[t] += y;
        __syncthreads();
    }
    int incl = tsum[t];
    int thread_prefix = incl - s;
    if (t == 255) partials[blockIdx.x] = incl;
#pragma unroll
    for (int i = 0; i < 4; ++i) {
        int idx = base + i;
        if (idx < n) offs[idx] = thread_prefix + v[i];
    }
}

__global__ void scan2_kernel(int* partials, int nb) {
    int t = threadIdx.x;
    int own = (t < nb) ? partials[t] : 0;
    int v = own;
    for (int off = 1; off < 64; off <<= 1) {
        int y = __shfl_up(v, off, 64);
        if (t >= off) v += y;
    }
    if (t < nb) partials[t] = v - own;
}

__global__ void scan3_kernel(int* __restrict__ offs, const int* __restrict__ partials, int n) {
    int base = blockIdx.x * 1024 + threadIdx.x;
    int add = partials[blockIdx.x];
#pragma unroll
    for (int i = 0; i < 4; ++i) {
        int idx = base + i * 256;
        if (idx < n) offs[idx] += add;
    }
}

// 16 lanes per edge: lane l handles elements [l*4, l*4+4). Each load instr
// covers 4 contiguous 256 B rows (coalesced), reduce is 4 shfl_xor levels
// within the 16-lane group. Leader lane does sigmoid + CSR slot + store.
// Mutates offs so afterwards offs[n] == inclusive segment end of node n.
__global__ void alpha_scatter_kernel(const int* __restrict__ edges, const int* __restrict__ r_idx,
                                     const float* __restrict__ hsW, const float* __restrict__ hrW,
                                     const float* __restrict__ qr_attn,
                                     const float* __restrict__ walpha_w,
                                     const float* __restrict__ walpha_b,
                                     int* __restrict__ offs, int2* __restrict__ rec, int E) {
    int tid = blockIdx.x * blockDim.x + threadIdx.x;
    int e = tid >> 4;          // one edge per 16-lane group
    int l = tid & 15;
    if (e >= E) return;
    int sub = edges[e * 3 + 0];
    int rel = edges[e * 3 + 1];
    int obj = edges[e * 3 + 2];
    int ri  = r_idx[e];
    float4 av = *(const float4*)(hsW + (size_t)sub * D64 + l * 4);
    float4 bv = *(const float4*)(hrW + (size_t)rel * D64 + l * 4);
    float4 cv = *(const float4*)(qr_attn + (size_t)ri * D64 + l * 4);
    float4 wv = *(const float4*)(walpha_w + l * 4);
    float x;
    x = fmaxf(av.x + bv.x + cv.x, 0.f) * wv.x;
    x = fmaf(fmaxf(av.y + bv.y + cv.y, 0.f), wv.y, x);
    x = fmaf(fmaxf(av.z + bv.z + cv.z, 0.f), wv.z, x);
    x = fmaf(fmaxf(av.w + bv.w + cv.w, 0.f), wv.w, x);
    // reduce within 16-lane group (xor masks < 16 stay in-group)
    x += __shfl_xor(x, 8, 64);
    x += __shfl_xor(x, 4, 64);
    x += __shfl_xor(x, 2, 64);
    x += __shfl_xor(x, 1, 64);
    if (l == 0) {
        float alpha = 1.f / (1.f + __expf(-(x + walpha_b[0])));
        int slot = atomicAdd(&offs[obj], 1);
        rec[slot] = make_int2(sub | (rel << 17), __float_as_int(alpha));
    }
}

// One wave per destination node. Stage up to 64 CSR records with one
// coalesced vector load, then iterate with readlane (uniform j -> SGPR
// record, SGPR-base coalesced row gathers, independent loads -> MLP).
__global__ void agg_kernel(const int2* __restrict__ rec, const int* __restrict__ endoff,
                           const float* __restrict__ hidden, const float* __restrict__ hrmap,
                           float* __restrict__ aggout, int NN) {
    int lane = threadIdx.x & 63;
    int n = (blockIdx.x * blockDim.x + threadIdx.x) >> 6;
    if (n >= NN) return;
    int start = (n == 0) ? 0 : endoff[n - 1];
    int end = endoff[n];
    start = __builtin_amdgcn_readfirstlane(start);
    end = __builtin_amdgcn_readfirstlane(end);
    float acc0 = 0.f, acc1 = 0.f;
    for (int base = start; base < end; base += 64) {
        int cnt = end - base;
        if (cnt > 64) cnt = 64;
        int rx = 0, ry = 0;
        if (lane < cnt) {
            int2 r = rec[base + lane];
            rx = r.x; ry = r.y;
        }
        int j = 0;
        for (; j + 1 < cnt; j += 2) {
            int rx0 = __builtin_amdgcn_readlane(rx, j);
            int ry0 = __builtin_amdgcn_readlane(ry, j);
            int rx1 = __builtin_amdgcn_readlane(rx, j + 1);
            int ry1 = __builtin_amdgcn_readlane(ry, j + 1);
            int s0 = rx0 & 0x1FFFF, e0 = ((unsigned)rx0) >> 17;
            int s1 = rx1 & 0x1FFFF, e1 = ((unsigned)rx1) >> 17;
            float h0 = hidden[(size_t)s0 * D64 + lane];
            float m0 = hrmap[(size_t)e0 * D64 + lane];
            float h1 = hidden[(size_t)s1 * D64 + lane];
            float m1 = hrmap[(size_t)e1 * D64 + lane];
            acc0 = fmaf(__uint_as_float(ry0) * h0, m0, acc0);
            acc1 = fmaf(__uint_as_float(ry1) * h1, m1, acc1);
        }
        if (j < cnt) {
            int rx0 = __builtin_amdgcn_readlane(rx, j);
            int ry0 = __builtin_amdgcn_readlane(ry, j);
            int s0 = rx0 & 0x1FFFF, e0 = ((unsigned)rx0) >> 17;
            float h0 = hidden[(size_t)s0 * D64 + lane];
            float m0 = hrmap[(size_t)e0 * D64 + lane];
            acc0 = fmaf(__uint_as_float(ry0) * h0, m0, acc0);
        }
    }
    aggout[(size_t)n * D64 + lane] = acc0 + acc1;
}

extern "C" void kernel_launch(void* const* d_in, const int* in_sizes, int n_in,
                              void* d_out, int out_size, void* d_ws, size_t ws_size,
                              hipStream_t stream) {
    const float* hidden   = (const float*)d_in[0];
    const int*   edges    = (const int*)d_in[1];
    const float* emb_rel  = (const float*)d_in[2];
    const int*   mapping  = (const int*)d_in[3];
    const int*   q_rel    = (const int*)d_in[4];
    const int*   r_idx    = (const int*)d_in[5];
    const float* Ws_w     = (const float*)d_in[7];
    const float* Wr_w     = (const float*)d_in[8];
    const float* Wqr_w    = (const float*)d_in[9];
    const float* Wqr_b    = (const float*)d_in[10];
    const float* walpha_w = (const float*)d_in[11];
    const float* walpha_b = (const float*)d_in[12];
    const float* Wh_w     = (const float*)d_in[13];
    float* out = (float*)d_out;

    int NN   = in_sizes[0] / D64;   // 50000
    int E    = in_sizes[5];         // 800000
    int NREL = in_sizes[3];         // 475
    int NQ   = in_sizes[4];         // 32

    // workspace layout
    char* ws = (char*)d_ws;
    size_t off = 0;
    float* hsW = (float*)(ws + off);      off += (size_t)NN * D64 * sizeof(float);   // 12.8 MB
    int2*  rec = (int2*)(ws + off);       off += (size_t)E * sizeof(int2);           // 6.4 MB
    int* counts = (int*)(ws + off);       off += (size_t)NN * sizeof(int);           // 0.2 MB
    int* offs   = (int*)(ws + off);       off += (size_t)NN * sizeof(int);           // 0.2 MB
    int* partials = (int*)(ws + off);     off += 64 * sizeof(int);
    float* hrmap = (float*)(ws + off);    off += (size_t)NREL * D64 * sizeof(float);
    float* hrW   = (float*)(ws + off);    off += (size_t)NREL * D64 * sizeof(float);
    float* qr_attn = (float*)(ws + off);  off += (size_t)NQ * D64 * sizeof(float);

    int NB = (NN + 1023) / 1024;  // scan blocks (49)

    hipMemsetAsync(counts, 0, (size_t)NN * sizeof(int), stream);
    prep_kernel<<<NREL + NQ, 64, 0, stream>>>(emb_rel, mapping, q_rel, Wr_w, Wqr_w, Wqr_b,
                                              hrmap, hrW, qr_attn, NREL, NQ);
    rowmm_kernel<false><<<1024, 256, 0, stream>>>(hidden, Ws_w, hsW, NN);
    hist_kernel<<<(E + 255) / 256, 256, 0, stream>>>(edges, counts, E);
    scan1_kernel<<<NB, 256, 0, stream>>>(counts, offs, partials, NN);
    scan2_kernel<<<1, 64, 0, stream>>>(partials, NB);
    scan3_kernel<<<NB, 256, 0, stream>>>(offs, partials, NN);
    {
        long long threads = (long long)E * 16;
        int blocks = (int)((threads + 255) / 256);
        alpha_scatter_kernel<<<blocks, 256, 0, stream>>>(edges, r_idx, hsW, hrW, qr_attn,
                                                         walpha_w, walpha_b, offs, rec, E);
    }
    // aggregate straight into d_out, then apply Wh in place
    agg_kernel<<<(NN * 64 + 255) / 256, 256, 0, stream>>>(rec, offs, hidden, hrmap, out, NN);
    rowmm_kernel<true><<<1024, 256, 0, stream>>>(out, Wh_w, out, NN);
}

// Round 6
// 181.175 us; speedup vs baseline: 1.6702x; 1.1033x over previous
//
#include <hip/hip_runtime.h>
#include <hip/hip_bf16.h>

#define D64 64

__device__ inline float lane_bcast(float v, int l) {
    return __uint_as_float(__builtin_amdgcn_readlane(__float_as_uint(v), l));
}
__device__ inline float bf16_lo(unsigned u) { return __uint_as_float(u << 16); }
__device__ inline float bf16_hi(unsigned u) { return __uint_as_float(u & 0xFFFF0000u); }
__device__ inline unsigned short f2bf(float f) {
    __hip_bfloat16 b = __float2bfloat16(f);
    return *(unsigned short*)&b;
}

// out[r][a] = relu(sum_d in[r][d] * W[a][d])   (W row-major [64][64])
// in/out intentionally NOT __restrict__ (runs in place on d_out).
__global__ void rowmm_relu_kernel(const float* in, const float* __restrict__ W,
                                  float* out, int nrows) {
    __shared__ float WT[D64 * D64];  // WT[d][a] = W[a][d]
    int tid = threadIdx.x;
    for (int i = tid; i < D64 * D64; i += blockDim.x)
        WT[(i & 63) * D64 + (i >> 6)] = W[i];
    __syncthreads();
    int lane = tid & 63;
    int wid = (blockIdx.x * blockDim.x + tid) >> 6;
    int nw = (gridDim.x * blockDim.x) >> 6;
    for (int r = wid; r < nrows; r += nw) {
        float v = in[r * D64 + lane];
        float acc = 0.f;
#pragma unroll
        for (int d = 0; d < D64; ++d)
            acc = fmaf(lane_bcast(v, d), WT[d * D64 + lane], acc);
        out[r * D64 + lane] = fmaxf(acc, 0.f);
    }
}

// hsWb[r][a] = bf16(sum_d in[r][d] * W[a][d]); also emits inb = bf16(in).
__global__ void rowmm_bf16_kernel(const float* __restrict__ in, const float* __restrict__ W,
                                  unsigned short* __restrict__ outb,
                                  unsigned short* __restrict__ inb, int nrows) {
    __shared__ float WT[D64 * D64];
    int tid = threadIdx.x;
    for (int i = tid; i < D64 * D64; i += blockDim.x)
        WT[(i & 63) * D64 + (i >> 6)] = W[i];
    __syncthreads();
    int lane = tid & 63;
    int wid = (blockIdx.x * blockDim.x + tid) >> 6;
    int nw = (gridDim.x * blockDim.x) >> 6;
    for (int r = wid; r < nrows; r += nw) {
        float v = in[r * D64 + lane];
        inb[r * D64 + lane] = f2bf(v);
        float acc = 0.f;
#pragma unroll
        for (int d = 0; d < D64; ++d)
            acc = fmaf(lane_bcast(v, d), WT[d * D64 + lane], acc);
        outb[r * D64 + lane] = f2bf(acc);
    }
}

// Per-relation tables: hrmap[r] = emb[mapping[r]]; hrW[r] = hrmap[r] @ Wr.T
// Per-query: qr_attn[q] = emb[mapping[q_rel[q]]] @ Wqr.T + Wqr_b
__global__ void prep_kernel(const float* __restrict__ emb, const int* __restrict__ mapping,
                            const int* __restrict__ q_rel,
                            const float* __restrict__ Wr, const float* __restrict__ Wqr,
                            const float* __restrict__ Wqr_b,
                            float* __restrict__ hrmap, float* __restrict__ hrW,
                            float* __restrict__ qr_attn, int nrel, int nq) {
    int b = blockIdx.x;
    int lane = threadIdx.x;
    if (b < nrel) {
        int m = mapping[b];
        float v = emb[m * D64 + lane];
        hrmap[b * D64 + lane] = v;
        float acc = 0.f;
#pragma unroll
        for (int d = 0; d < D64; ++d)
            acc = fmaf(lane_bcast(v, d), Wr[lane * D64 + d], acc);
        hrW[b * D64 + lane] = acc;
    } else {
        int q = b - nrel;
        if (q < nq) {
            int m = mapping[q_rel[q]];
            float v = emb[m * D64 + lane];
            float acc = Wqr_b[lane];
#pragma unroll
            for (int d = 0; d < D64; ++d)
                acc = fmaf(lane_bcast(v, d), Wqr[lane * D64 + d], acc);
            qr_attn[q * D64 + lane] = acc;
        }
    }
}

__global__ void hist_kernel(const int* __restrict__ edges, int* __restrict__ counts, int E) {
    int i = blockIdx.x * blockDim.x + threadIdx.x;
    if (i < E) atomicAdd(&counts[edges[i * 3 + 2]], 1);
}

// Block-level exclusive scan: 1024 elements/block (256 thr x 4).
__global__ void scan1_kernel(const int* __restrict__ counts, int* __restrict__ offs,
                             int* __restrict__ partials, int n) {
    __shared__ int tsum[256];
    int t = threadIdx.x;
    int base = blockIdx.x * 1024 + t * 4;
    int v[4];
    int s = 0;
#pragma unroll
    for (int i = 0; i < 4; ++i) {
        int idx = base + i;
        int c = (idx < n) ? counts[idx] : 0;
        v[i] = s;
        s += c;
    }
    tsum[t] = s;
    __syncthreads();
    for (int off = 1; off < 256; off <<= 1) {
        int y = (t >= off) ? tsum[t - off] : 0;
        __syncthreads();
        tsum[t] += y;
        __syncthreads();
    }
    int incl = tsum[t];
    int thread_prefix = incl - s;
    if (t == 255) partials[blockIdx.x] = incl;
#pragma unroll
    for (int i = 0; i < 4; ++i) {
        int idx = base + i;
        if (idx < n) offs[idx] = thread_prefix + v[i];
    }
}

__global__ void scan2_kernel(int* partials, int nb) {
    int t = threadIdx.x;
    int own = (t < nb) ? partials[t] : 0;
    int v = own;
    for (int off = 1; off < 64; off <<= 1) {
        int y = __shfl_up(v, off, 64);
        if (t >= off) v += y;
    }
    if (t < nb) partials[t] = v - own;
}

__global__ void scan3_kernel(int* __restrict__ offs, const int* __restrict__ partials, int n) {
    int base = blockIdx.x * 1024 + threadIdx.x;
    int add = partials[blockIdx.x];
#pragma unroll
    for (int i = 0; i < 4; ++i) {
        int idx = base + i * 256;
        if (idx < n) offs[idx] += add;
    }
}

// 8 lanes per edge: lane l handles bf16 elements [l*8, l*8+8) of the hsW row
// (one uint4 = 16 B), f32 tables hrW/qr_attn are L2-hot. 3-level intra-group
// reduce; leader does sigmoid + CSR slot + rec store.
// Mutates offs so afterwards offs[n] == inclusive segment end of node n.
__global__ void alpha_scatter_kernel(const int* __restrict__ edges, const int* __restrict__ r_idx,
                                     const unsigned short* __restrict__ hsWb,
                                     const float* __restrict__ hrW,
                                     const float* __restrict__ qr_attn,
                                     const float* __restrict__ walpha_w,
                                     const float* __restrict__ walpha_b,
                                     int* __restrict__ offs, int2* __restrict__ rec, int E) {
    int tid = blockIdx.x * blockDim.x + threadIdx.x;
    int e = tid >> 3;          // one edge per 8-lane group
    int l = tid & 7;
    if (e >= E) return;
    int sub = edges[e * 3 + 0];
    int rel = edges[e * 3 + 1];
    int obj = edges[e * 3 + 2];
    int ri  = r_idx[e];
    uint4 hv = *(const uint4*)(hsWb + (size_t)sub * D64 + l * 8);
    const float4* b = (const float4*)(hrW + (size_t)rel * D64 + l * 8);
    const float4* c = (const float4*)(qr_attn + (size_t)ri * D64 + l * 8);
    const float4* w = (const float4*)(walpha_w + l * 8);
    float4 b0 = b[0], b1 = b[1], c0 = c[0], c1 = c[1], w0 = w[0], w1 = w[1];
    float x;
    x = fmaxf(bf16_lo(hv.x) + b0.x + c0.x, 0.f) * w0.x;
    x = fmaf(fmaxf(bf16_hi(hv.x) + b0.y + c0.y, 0.f), w0.y, x);
    x = fmaf(fmaxf(bf16_lo(hv.y) + b0.z + c0.z, 0.f), w0.z, x);
    x = fmaf(fmaxf(bf16_hi(hv.y) + b0.w + c0.w, 0.f), w0.w, x);
    x = fmaf(fmaxf(bf16_lo(hv.z) + b1.x + c1.x, 0.f), w1.x, x);
    x = fmaf(fmaxf(bf16_hi(hv.z) + b1.y + c1.y, 0.f), w1.y, x);
    x = fmaf(fmaxf(bf16_lo(hv.w) + b1.z + c1.z, 0.f), w1.z, x);
    x = fmaf(fmaxf(bf16_hi(hv.w) + b1.w + c1.w, 0.f), w1.w, x);
    // reduce within 8-lane group
    x += __shfl_xor(x, 4, 64);
    x += __shfl_xor(x, 2, 64);
    x += __shfl_xor(x, 1, 64);
    if (l == 0) {
        float alpha = 1.f / (1.f + __expf(-(x + walpha_b[0])));
        int slot = atomicAdd(&offs[obj], 1);
        rec[slot] = make_int2(sub | (rel << 17), __float_as_int(alpha));
    }
}

// One wave per destination node. Stage up to 64 CSR records with one
// coalesced vector load, then iterate with readlane (uniform j -> SGPR
// record, SGPR-base coalesced row gathers, independent loads -> MLP).
// hidden gathered as bf16 (128 B/row), hrmap f32 (L2-hot).
__global__ void agg_kernel(const int2* __restrict__ rec, const int* __restrict__ endoff,
                           const unsigned short* __restrict__ hiddenb,
                           const float* __restrict__ hrmap,
                           float* __restrict__ aggout, int NN) {
    int lane = threadIdx.x & 63;
    int n = (blockIdx.x * blockDim.x + threadIdx.x) >> 6;
    if (n >= NN) return;
    int start = (n == 0) ? 0 : endoff[n - 1];
    int end = endoff[n];
    start = __builtin_amdgcn_readfirstlane(start);
    end = __builtin_amdgcn_readfirstlane(end);
    float acc0 = 0.f, acc1 = 0.f;
    for (int base = start; base < end; base += 64) {
        int cnt = end - base;
        if (cnt > 64) cnt = 64;
        int rx = 0, ry = 0;
        if (lane < cnt) {
            int2 r = rec[base + lane];
            rx = r.x; ry = r.y;
        }
        int j = 0;
        for (; j + 1 < cnt; j += 2) {
            int rx0 = __builtin_amdgcn_readlane(rx, j);
            int ry0 = __builtin_amdgcn_readlane(ry, j);
            int rx1 = __builtin_amdgcn_readlane(rx, j + 1);
            int ry1 = __builtin_amdgcn_readlane(ry, j + 1);
            int s0 = rx0 & 0x1FFFF, e0 = ((unsigned)rx0) >> 17;
            int s1 = rx1 & 0x1FFFF, e1 = ((unsigned)rx1) >> 17;
            float h0 = __uint_as_float((unsigned)hiddenb[(size_t)s0 * D64 + lane] << 16);
            float m0 = hrmap[(size_t)e0 * D64 + lane];
            float h1 = __uint_as_float((unsigned)hiddenb[(size_t)s1 * D64 + lane] << 16);
            float m1 = hrmap[(size_t)e1 * D64 + lane];
            acc0 = fmaf(__uint_as_float(ry0) * h0, m0, acc0);
            acc1 = fmaf(__uint_as_float(ry1) * h1, m1, acc1);
        }
        if (j < cnt) {
            int rx0 = __builtin_amdgcn_readlane(rx, j);
            int ry0 = __builtin_amdgcn_readlane(ry, j);
            int s0 = rx0 & 0x1FFFF, e0 = ((unsigned)rx0) >> 17;
            float h0 = __uint_as_float((unsigned)hiddenb[(size_t)s0 * D64 + lane] << 16);
            float m0 = hrmap[(size_t)e0 * D64 + lane];
            acc0 = fmaf(__uint_as_float(ry0) * h0, m0, acc0);
        }
    }
    aggout[(size_t)n * D64 + lane] = acc0 + acc1;
}

extern "C" void kernel_launch(void* const* d_in, const int* in_sizes, int n_in,
                              void* d_out, int out_size, void* d_ws, size_t ws_size,
                              hipStream_t stream) {
    const float* hidden   = (const float*)d_in[0];
    const int*   edges    = (const int*)d_in[1];
    const float* emb_rel  = (const float*)d_in[2];
    const int*   mapping  = (const int*)d_in[3];
    const int*   q_rel    = (const int*)d_in[4];
    const int*   r_idx    = (const int*)d_in[5];
    const float* Ws_w     = (const float*)d_in[7];
    const float* Wr_w     = (const float*)d_in[8];
    const float* Wqr_w    = (const float*)d_in[9];
    const float* Wqr_b    = (const float*)d_in[10];
    const float* walpha_w = (const float*)d_in[11];
    const float* walpha_b = (const float*)d_in[12];
    const float* Wh_w     = (const float*)d_in[13];
    float* out = (float*)d_out;

    int NN   = in_sizes[0] / D64;   // 50000
    int E    = in_sizes[5];         // 800000
    int NREL = in_sizes[3];         // 475
    int NQ   = in_sizes[4];         // 32

    // workspace layout
    char* ws = (char*)d_ws;
    size_t off = 0;
    unsigned short* hsWb    = (unsigned short*)(ws + off); off += (size_t)NN * D64 * 2;  // 6.4 MB
    unsigned short* hiddenb = (unsigned short*)(ws + off); off += (size_t)NN * D64 * 2;  // 6.4 MB
    int2*  rec = (int2*)(ws + off);       off += (size_t)E * sizeof(int2);               // 6.4 MB
    int* counts = (int*)(ws + off);       off += (size_t)NN * sizeof(int);               // 0.2 MB
    int* offs   = (int*)(ws + off);       off += (size_t)NN * sizeof(int);               // 0.2 MB
    int* partials = (int*)(ws + off);     off += 64 * sizeof(int);
    float* hrmap = (float*)(ws + off);    off += (size_t)NREL * D64 * sizeof(float);
    float* hrW   = (float*)(ws + off);    off += (size_t)NREL * D64 * sizeof(float);
    float* qr_attn = (float*)(ws + off);  off += (size_t)NQ * D64 * sizeof(float);

    int NB = (NN + 1023) / 1024;  // scan blocks (49)

    hipMemsetAsync(counts, 0, (size_t)NN * sizeof(int), stream);
    prep_kernel<<<NREL + NQ, 64, 0, stream>>>(emb_rel, mapping, q_rel, Wr_w, Wqr_w, Wqr_b,
                                              hrmap, hrW, qr_attn, NREL, NQ);
    rowmm_bf16_kernel<<<1024, 256, 0, stream>>>(hidden, Ws_w, hsWb, hiddenb, NN);
    hist_kernel<<<(E + 255) / 256, 256, 0, stream>>>(edges, counts, E);
    scan1_kernel<<<NB, 256, 0, stream>>>(counts, offs, partials, NN);
    scan2_kernel<<<1, 64, 0, stream>>>(partials, NB);
    scan3_kernel<<<NB, 256, 0, stream>>>(offs, partials, NN);
    {
        long long threads = (long long)E * 8;
        int blocks = (int)((threads + 255) / 256);
        alpha_scatter_kernel<<<blocks, 256, 0, stream>>>(edges, r_idx, hsWb, hrW, qr_attn,
                                                         walpha_w, walpha_b, offs, rec, E);
    }
    // aggregate straight into d_out, then apply Wh in place
    agg_kernel<<<(NN * 64 + 255) / 256, 256, 0, stream>>>(rec, offs, hiddenb, hrmap, out, NN);
    rowmm_relu_kernel<<<1024, 256, 0, stream>>>(out, Wh_w, out, NN);
}

// Round 7
// 172.012 us; speedup vs baseline: 1.7591x; 1.0533x over previous
//
#include <hip/hip_runtime.h>
#include <hip/hip_bf16.h>

#define D64 64

__device__ inline float lane_bcast(float v, int l) {
    return __uint_as_float(__builtin_amdgcn_readlane(__float_as_uint(v), l));
}
__device__ inline float bf16_lo(unsigned u) { return __uint_as_float(u << 16); }
__device__ inline float bf16_hi(unsigned u) { return __uint_as_float(u & 0xFFFF0000u); }
__device__ inline unsigned short f2bf(float f) {
    __hip_bfloat16 b = __float2bfloat16(f);
    return *(unsigned short*)&b;
}

// hsWb[r][a] = bf16(sum_d in[r][d] * Ws[a][d]); also emits inb = bf16(in),
// and runs the obj histogram as an independent second loop (hides under VALU).
__global__ void rowmm_bf16_hist_kernel(const float* __restrict__ in, const float* __restrict__ W,
                                       unsigned short* __restrict__ outb,
                                       unsigned short* __restrict__ inb, int nrows,
                                       const int* __restrict__ edges, int* __restrict__ counts,
                                       int E) {
    __shared__ float WT[D64 * D64];
    int tid = threadIdx.x;
    for (int i = tid; i < D64 * D64; i += blockDim.x)
        WT[(i & 63) * D64 + (i >> 6)] = W[i];
    __syncthreads();
    int lane = tid & 63;
    int wid = (blockIdx.x * blockDim.x + tid) >> 6;
    int nw = (gridDim.x * blockDim.x) >> 6;
    for (int r = wid; r < nrows; r += nw) {
        float v = in[r * D64 + lane];
        inb[r * D64 + lane] = f2bf(v);
        float acc = 0.f;
#pragma unroll
        for (int d = 0; d < D64; ++d)
            acc = fmaf(lane_bcast(v, d), WT[d * D64 + lane], acc);
        outb[r * D64 + lane] = f2bf(acc);
    }
    // histogram of obj
    int gt = blockIdx.x * blockDim.x + tid;
    int gs = gridDim.x * blockDim.x;
    for (int i = gt; i < E; i += gs)
        atomicAdd(&counts[edges[i * 3 + 2]], 1);
}

// Per-relation tables: hrmap[r] = emb[mapping[r]]; hrW[r] = hrmap[r] @ Wr.T
// Per-query: qr_attn[q] = emb[mapping[q_rel[q]]] @ Wqr.T + Wqr_b
__global__ void prep_kernel(const float* __restrict__ emb, const int* __restrict__ mapping,
                            const int* __restrict__ q_rel,
                            const float* __restrict__ Wr, const float* __restrict__ Wqr,
                            const float* __restrict__ Wqr_b,
                            float* __restrict__ hrmap, float* __restrict__ hrW,
                            float* __restrict__ qr_attn, int nrel, int nq) {
    int b = blockIdx.x;
    int lane = threadIdx.x;
    if (b < nrel) {
        int m = mapping[b];
        float v = emb[m * D64 + lane];
        hrmap[b * D64 + lane] = v;
        float acc = 0.f;
#pragma unroll
        for (int d = 0; d < D64; ++d)
            acc = fmaf(lane_bcast(v, d), Wr[lane * D64 + d], acc);
        hrW[b * D64 + lane] = acc;
    } else {
        int q = b - nrel;
        if (q < nq) {
            int m = mapping[q_rel[q]];
            float v = emb[m * D64 + lane];
            float acc = Wqr_b[lane];
#pragma unroll
            for (int d = 0; d < D64; ++d)
                acc = fmaf(lane_bcast(v, d), Wqr[lane * D64 + d], acc);
            qr_attn[q * D64 + lane] = acc;
        }
    }
}

// Block-level exclusive scan: 1024 elements/block (256 thr x 4).
__global__ void scan1_kernel(const int* __restrict__ counts, int* __restrict__ offs,
                             int* __restrict__ partials, int n) {
    __shared__ int tsum[256];
    int t = threadIdx.x;
    int base = blockIdx.x * 1024 + t * 4;
    int v[4];
    int s = 0;
#pragma unroll
    for (int i = 0; i < 4; ++i) {
        int idx = base + i;
        int c = (idx < n) ? counts[idx] : 0;
        v[i] = s;
        s += c;
    }
    tsum[t] = s;
    __syncthreads();
    for (int off = 1; off < 256; off <<= 1) {
        int y = (t >= off) ? tsum[t - off] : 0;
        __syncthreads();
        tsum[t] += y;
        __syncthreads();
    }
    int incl = tsum[t];
    int thread_prefix = incl - s;
    if (t == 255) partials[blockIdx.x] = incl;
#pragma unroll
    for (int i = 0; i < 4; ++i) {
        int idx = base + i;
        if (idx < n) offs[idx] = thread_prefix + v[i];
    }
}

__global__ void scan2_kernel(int* partials, int nb) {
    int t = threadIdx.x;
    int own = (t < nb) ? partials[t] : 0;
    int v = own;
    for (int off = 1; off < 64; off <<= 1) {
        int y = __shfl_up(v, off, 64);
        if (t >= off) v += y;
    }
    if (t < nb) partials[t] = v - own;
}

__global__ void scan3_kernel(int* __restrict__ offs, const int* __restrict__ partials, int n) {
    int base = blockIdx.x * 1024 + threadIdx.x;
    int add = partials[blockIdx.x];
#pragma unroll
    for (int i = 0; i < 4; ++i) {
        int idx = base + i * 256;
        if (idx < n) offs[idx] += add;
    }
}

// 8 lanes per edge, TWO edges per thread (e and e+half) with interleaved
// loads for memory-level parallelism. Leader lane: sigmoid + CSR slot + store.
// Mutates offs so afterwards offs[n] == inclusive segment end of node n.
__global__ void alpha_scatter_kernel(const int* __restrict__ edges, const int* __restrict__ r_idx,
                                     const unsigned short* __restrict__ hsWb,
                                     const float* __restrict__ hrW,
                                     const float* __restrict__ qr_attn,
                                     const float* __restrict__ walpha_w,
                                     const float* __restrict__ walpha_b,
                                     int* __restrict__ offs, int2* __restrict__ rec,
                                     int E, int half) {
    int tid = blockIdx.x * blockDim.x + threadIdx.x;
    int e0 = tid >> 3;
    int l = tid & 7;
    if (e0 >= half) return;
    int e1 = e0 + half;
    bool has1 = (e1 < E);

    int sub0 = edges[e0 * 3 + 0];
    int rel0 = edges[e0 * 3 + 1];
    int obj0 = edges[e0 * 3 + 2];
    int ri0  = r_idx[e0];
    int sub1 = 0, rel1 = 0, obj1 = 0, ri1 = 0;
    if (has1) {
        sub1 = edges[e1 * 3 + 0];
        rel1 = edges[e1 * 3 + 1];
        obj1 = edges[e1 * 3 + 2];
        ri1  = r_idx[e1];
    }
    // issue both row gathers before any use
    uint4 hv0 = *(const uint4*)(hsWb + (size_t)sub0 * D64 + l * 8);
    uint4 hv1 = has1 ? *(const uint4*)(hsWb + (size_t)sub1 * D64 + l * 8) : make_uint4(0,0,0,0);
    const float4* b0p = (const float4*)(hrW + (size_t)rel0 * D64 + l * 8);
    const float4* c0p = (const float4*)(qr_attn + (size_t)ri0 * D64 + l * 8);
    const float4* b1p = (const float4*)(hrW + (size_t)rel1 * D64 + l * 8);
    const float4* c1p = (const float4*)(qr_attn + (size_t)ri1 * D64 + l * 8);
    const float4* w = (const float4*)(walpha_w + l * 8);
    float4 w0 = w[0], w1 = w[1];
    float4 b00 = b0p[0], b01 = b0p[1], c00 = c0p[0], c01 = c0p[1];
    float4 b10 = b1p[0], b11 = b1p[1], c10 = c1p[0], c11 = c1p[1];

    float x0, x1;
    x0 = fmaxf(bf16_lo(hv0.x) + b00.x + c00.x, 0.f) * w0.x;
    x0 = fmaf(fmaxf(bf16_hi(hv0.x) + b00.y + c00.y, 0.f), w0.y, x0);
    x0 = fmaf(fmaxf(bf16_lo(hv0.y) + b00.z + c00.z, 0.f), w0.z, x0);
    x0 = fmaf(fmaxf(bf16_hi(hv0.y) + b00.w + c00.w, 0.f), w0.w, x0);
    x0 = fmaf(fmaxf(bf16_lo(hv0.z) + b01.x + c01.x, 0.f), w1.x, x0);
    x0 = fmaf(fmaxf(bf16_hi(hv0.z) + b01.y + c01.y, 0.f), w1.y, x0);
    x0 = fmaf(fmaxf(bf16_lo(hv0.w) + b01.z + c01.z, 0.f), w1.z, x0);
    x0 = fmaf(fmaxf(bf16_hi(hv0.w) + b01.w + c01.w, 0.f), w1.w, x0);

    x1 = fmaxf(bf16_lo(hv1.x) + b10.x + c10.x, 0.f) * w0.x;
    x1 = fmaf(fmaxf(bf16_hi(hv1.x) + b10.y + c10.y, 0.f), w0.y, x1);
    x1 = fmaf(fmaxf(bf16_lo(hv1.y) + b10.z + c10.z, 0.f), w0.z, x1);
    x1 = fmaf(fmaxf(bf16_hi(hv1.y) + b10.w + c10.w, 0.f), w0.w, x1);
    x1 = fmaf(fmaxf(bf16_lo(hv1.z) + b11.x + c11.x, 0.f), w1.x, x1);
    x1 = fmaf(fmaxf(bf16_hi(hv1.z) + b11.y + c11.y, 0.f), w1.y, x1);
    x1 = fmaf(fmaxf(bf16_lo(hv1.w) + b11.z + c11.z, 0.f), w1.z, x1);
    x1 = fmaf(fmaxf(bf16_hi(hv1.w) + b11.w + c11.w, 0.f), w1.w, x1);

    x0 += __shfl_xor(x0, 4, 64);
    x1 += __shfl_xor(x1, 4, 64);
    x0 += __shfl_xor(x0, 2, 64);
    x1 += __shfl_xor(x1, 2, 64);
    x0 += __shfl_xor(x0, 1, 64);
    x1 += __shfl_xor(x1, 1, 64);

    if (l == 0) {
        float wb = walpha_b[0];
        float a0 = 1.f / (1.f + __expf(-(x0 + wb)));
        int slot0 = atomicAdd(&offs[obj0], 1);
        rec[slot0] = make_int2(sub0 | (rel0 << 17), __float_as_int(a0));
        if (has1) {
            float a1 = 1.f / (1.f + __expf(-(x1 + wb)));
            int slot1 = atomicAdd(&offs[obj1], 1);
            rec[slot1] = make_int2(sub1 | (rel1 << 17), __float_as_int(a1));
        }
    }
}

// One wave per destination node: CSR gather-FMA, then fused Wh matvec + relu.
// Stage up to 64 CSR records with one coalesced vector load, iterate with
// readlane (uniform j -> SGPR record -> coalesced row gathers, MLP-friendly).
__global__ void agg_wh_kernel(const int2* __restrict__ rec, const int* __restrict__ endoff,
                              const unsigned short* __restrict__ hiddenb,
                              const float* __restrict__ hrmap,
                              const float* __restrict__ Wh,
                              float* __restrict__ out, int NN) {
    __shared__ float WT[D64 * D64];  // WT[d][a] = Wh[a][d]
    int tid = threadIdx.x;
    for (int i = tid; i < D64 * D64; i += blockDim.x)
        WT[(i & 63) * D64 + (i >> 6)] = Wh[i];
    __syncthreads();
    int lane = tid & 63;
    int n = (blockIdx.x * blockDim.x + tid) >> 6;
    if (n >= NN) return;
    int start = (n == 0) ? 0 : endoff[n - 1];
    int end = endoff[n];
    start = __builtin_amdgcn_readfirstlane(start);
    end = __builtin_amdgcn_readfirstlane(end);
    float acc0 = 0.f, acc1 = 0.f;
    for (int base = start; base < end; base += 64) {
        int cnt = end - base;
        if (cnt > 64) cnt = 64;
        int rx = 0, ry = 0;
        if (lane < cnt) {
            int2 r = rec[base + lane];
            rx = r.x; ry = r.y;
        }
        int j = 0;
        for (; j + 1 < cnt; j += 2) {
            int rx0 = __builtin_amdgcn_readlane(rx, j);
            int ry0 = __builtin_amdgcn_readlane(ry, j);
            int rx1 = __builtin_amdgcn_readlane(rx, j + 1);
            int ry1 = __builtin_amdgcn_readlane(ry, j + 1);
            int s0 = rx0 & 0x1FFFF, e0 = ((unsigned)rx0) >> 17;
            int s1 = rx1 & 0x1FFFF, e1 = ((unsigned)rx1) >> 17;
            float h0 = __uint_as_float((unsigned)hiddenb[(size_t)s0 * D64 + lane] << 16);
            float m0 = hrmap[(size_t)e0 * D64 + lane];
            float h1 = __uint_as_float((unsigned)hiddenb[(size_t)s1 * D64 + lane] << 16);
            float m1 = hrmap[(size_t)e1 * D64 + lane];
            acc0 = fmaf(__uint_as_float(ry0) * h0, m0, acc0);
            acc1 = fmaf(__uint_as_float(ry1) * h1, m1, acc1);
        }
        if (j < cnt) {
            int rx0 = __builtin_amdgcn_readlane(rx, j);
            int ry0 = __builtin_amdgcn_readlane(ry, j);
            int s0 = rx0 & 0x1FFFF, e0 = ((unsigned)rx0) >> 17;
            float h0 = __uint_as_float((unsigned)hiddenb[(size_t)s0 * D64 + lane] << 16);
            float m0 = hrmap[(size_t)e0 * D64 + lane];
            acc0 = fmaf(__uint_as_float(ry0) * h0, m0, acc0);
        }
    }
    float acc = acc0 + acc1;
    // fused out[n] = relu(acc @ Wh.T)
    float o = 0.f;
#pragma unroll
    for (int d = 0; d < D64; ++d)
        o = fmaf(lane_bcast(acc, d), WT[d * D64 + lane], o);
    out[(size_t)n * D64 + lane] = fmaxf(o, 0.f);
}

extern "C" void kernel_launch(void* const* d_in, const int* in_sizes, int n_in,
                              void* d_out, int out_size, void* d_ws, size_t ws_size,
                              hipStream_t stream) {
    const float* hidden   = (const float*)d_in[0];
    const int*   edges    = (const int*)d_in[1];
    const float* emb_rel  = (const float*)d_in[2];
    const int*   mapping  = (const int*)d_in[3];
    const int*   q_rel    = (const int*)d_in[4];
    const int*   r_idx    = (const int*)d_in[5];
    const float* Ws_w     = (const float*)d_in[7];
    const float* Wr_w     = (const float*)d_in[8];
    const float* Wqr_w    = (const float*)d_in[9];
    const float* Wqr_b    = (const float*)d_in[10];
    const float* walpha_w = (const float*)d_in[11];
    const float* walpha_b = (const float*)d_in[12];
    const float* Wh_w     = (const float*)d_in[13];
    float* out = (float*)d_out;

    int NN   = in_sizes[0] / D64;   // 50000
    int E    = in_sizes[5];         // 800000
    int NREL = in_sizes[3];         // 475
    int NQ   = in_sizes[4];         // 32

    // workspace layout
    char* ws = (char*)d_ws;
    size_t off = 0;
    unsigned short* hsWb    = (unsigned short*)(ws + off); off += (size_t)NN * D64 * 2;  // 6.4 MB
    unsigned short* hiddenb = (unsigned short*)(ws + off); off += (size_t)NN * D64 * 2;  // 6.4 MB
    int2*  rec = (int2*)(ws + off);       off += (size_t)E * sizeof(int2);               // 6.4 MB
    int* counts = (int*)(ws + off);       off += (size_t)NN * sizeof(int);               // 0.2 MB
    int* offs   = (int*)(ws + off);       off += (size_t)NN * sizeof(int);               // 0.2 MB
    int* partials = (int*)(ws + off);     off += 64 * sizeof(int);
    float* hrmap = (float*)(ws + off);    off += (size_t)NREL * D64 * sizeof(float);
    float* hrW   = (float*)(ws + off);    off += (size_t)NREL * D64 * sizeof(float);
    float* qr_attn = (float*)(ws + off);  off += (size_t)NQ * D64 * sizeof(float);

    int NB = (NN + 1023) / 1024;  // scan blocks (49)

    hipMemsetAsync(counts, 0, (size_t)NN * sizeof(int), stream);
    prep_kernel<<<NREL + NQ, 64, 0, stream>>>(emb_rel, mapping, q_rel, Wr_w, Wqr_w, Wqr_b,
                                              hrmap, hrW, qr_attn, NREL, NQ);
    rowmm_bf16_hist_kernel<<<1024, 256, 0, stream>>>(hidden, Ws_w, hsWb, hiddenb, NN,
                                                     edges, counts, E);
    scan1_kernel<<<NB, 256, 0, stream>>>(counts, offs, partials, NN);
    scan2_kernel<<<1, 64, 0, stream>>>(partials, NB);
    scan3_kernel<<<NB, 256, 0, stream>>>(offs, partials, NN);
    {
        int half = (E + 1) / 2;
        long long threads = (long long)half * 8;
        int blocks = (int)((threads + 255) / 256);
        alpha_scatter_kernel<<<blocks, 256, 0, stream>>>(edges, r_idx, hsWb, hrW, qr_attn,
                                                         walpha_w, walpha_b, offs, rec, E, half);
    }
    agg_wh_kernel<<<(NN * 64 + 1023) / 1024, 1024, 0, stream>>>(rec, offs, hiddenb, hrmap,
                                                                Wh_w, out, NN);
}